// Round 4
// baseline (946.852 us; speedup 1.0000x reference)
//
#include <hip/hip_runtime.h>
#include <cstdint>
#include <cstddef>

// Problem constants: B=64, TQ=64, TP=1024, H=A=1024
typedef unsigned short u16;
typedef __bf16 bf16x8 __attribute__((ext_vector_type(8)));
typedef float floatx4 __attribute__((ext_vector_type(4)));

__device__ __forceinline__ u16 f32_to_bf16(float f) {
    unsigned u = __builtin_bit_cast(unsigned, f);
    u += 0x7fffu + ((u >> 16) & 1u);   // round-to-nearest-even
    return (u16)(u >> 16);
}
__device__ __forceinline__ unsigned pack_bf16x2(float lo, float hi) {
    return (unsigned)f32_to_bf16(lo) | ((unsigned)f32_to_bf16(hi) << 16);
}
__device__ __forceinline__ float bf16_lo(unsigned u) {
    return __builtin_bit_cast(float, u << 16);
}
__device__ __forceinline__ float bf16_hi(unsigned u) {
    return __builtin_bit_cast(float, u & 0xffff0000u);
}
__device__ __forceinline__ float bf16f(u16 v) {
    return __builtin_bit_cast(float, (unsigned)v << 16);
}
__device__ __forceinline__ float fast_tanh(float x) {
    float e = __expf(2.0f * x);
    return 1.0f - 2.0f * __builtin_amdgcn_rcpf(e + 1.0f);
}
__device__ __forceinline__ float fast_sigmoid(float x) {
    return __builtin_amdgcn_rcpf(1.0f + __expf(-x));
}
// async global->LDS, 16 B per lane. LDS dest is wave-uniform base + lane*16.
__device__ __forceinline__ void async_copy16(void* lds, const void* g) {
    __builtin_amdgcn_global_load_lds((const __attribute__((address_space(1))) void*)g,
                                     (__attribute__((address_space(3))) void*)lds,
                                     16, 0, 0);
}

// ---------------------------------------------------------------------------
// Merged fp32 -> bf16 bulk convert for passage (32768 blocks) + question (2048).
// Each thread: 8 floats -> one 16B store.
// ---------------------------------------------------------------------------
__global__ __launch_bounds__(256) void conv2_bf16_kernel(
    const float* __restrict__ p, u16* __restrict__ pout,
    const float* __restrict__ q, u16* __restrict__ qout)
{
    const int blk = blockIdx.x;
    const float* in;
    u16* out;
    size_t base;
    if (blk < 32768) { in = p; out = pout; base = (size_t)blk * 2048; }
    else             { in = q; out = qout; base = (size_t)(blk - 32768) * 2048; }
    const size_t i = base + (size_t)threadIdx.x * 8;
    float4 a = *(const float4*)(in + i);
    float4 b = *(const float4*)(in + i + 4);
    uint4 o;
    o.x = pack_bf16x2(a.x, a.y);
    o.y = pack_bf16x2(a.z, a.w);
    o.z = pack_bf16x2(b.x, b.y);
    o.w = pack_bf16x2(b.z, b.w);
    *(uint4*)(out + i) = o;
}

// ---------------------------------------------------------------------------
// Merged transpose+convert: W fp32 [K,N] -> WT bf16 [N,K]; blockIdx.z picks pair.
// ---------------------------------------------------------------------------
__global__ __launch_bounds__(256) void transpose2_bf16_kernel(
    const float* __restrict__ W0, u16* __restrict__ WT0,
    const float* __restrict__ W1, u16* __restrict__ WT1)
{
    const float* W = blockIdx.z ? W1 : W0;
    u16* WT        = blockIdx.z ? WT1 : WT0;
    const int K = 1024, N = 1024;
    __shared__ float tile[32][33];
    const int k0 = blockIdx.y * 32, n0 = blockIdx.x * 32;
    const int tid = threadIdx.x;
#pragma unroll
    for (int i = 0; i < 4; ++i) {
        int e = tid + i * 256, rr = e >> 5, cc = e & 31;
        tile[rr][cc] = W[(size_t)(k0 + rr) * N + (n0 + cc)];
    }
    __syncthreads();
#pragma unroll
    for (int i = 0; i < 4; ++i) {
        int e = tid + i * 256, rr = e >> 5, cc = e & 31;
        WT[(size_t)(n0 + rr) * K + (k0 + cc)] = f32_to_bf16(tile[cc][rr]);
    }
}

// ---------------------------------------------------------------------------
// vWq[a] += sum_{h in chunk} V_q[h] * Wq_q[h,a].  grid (4, 8), atomicAdd.
// ---------------------------------------------------------------------------
__global__ __launch_bounds__(256) void vq_proj_kernel(
    const float* __restrict__ Vq, const float* __restrict__ Wq, float* __restrict__ out)
{
    const int a = blockIdx.x * 256 + threadIdx.x;
    const int h0 = blockIdx.y * 128;
    float acc = 0.f;
#pragma unroll 8
    for (int h = h0; h < h0 + 128; ++h)
        acc += Vq[h] * Wq[(size_t)h * 1024 + a];
    atomicAdd(&out[a], acc);
}

// ---------------------------------------------------------------------------
// m97-structure GEMM: C[M,N] bf16 = A bf16 [M,K] @ (BT bf16 [N,K])^T
// 128x128 tile, BK=32, 4 waves (2x2), 16x16x32 bf16 MFMA, 4x4 frags/wave.
// Staging via global_load_lds dwordx4 (16B/lane).
// OPERANDS SWAPPED in the MFMA call -> D holds C^T in fragment space:
//   thread's frag (i,j): row m = wm+i*16+(lane&15), cols n = wn+j*16+quad*4+[0..3]
// -> C-store is 16 packed dwordx2 per thread; fused logit reduce needs only
//    2 shfls (over the quad dim) per row group.
// FUSE: 1-D grid, XCD swizzle (xcd=blk&7; 8 consecutive blocks per XCD share an
// m-stripe -> A-stripe L2-resident); epilogue adds begin-logit partials:
//   sOut[m] += sum_n tanh(acc + shift[b,n]) * wv[n]   (atomicAdd)
// ---------------------------------------------------------------------------
template <bool FUSE>
__global__ __launch_bounds__(256) void gemm_bf16_kernel(
    const u16* __restrict__ A, const u16* __restrict__ BT,
    u16* __restrict__ C, const float* __restrict__ shift,
    const float* __restrict__ wv, float* __restrict__ sOut, int K, int N)
{
    __shared__ __align__(16) u16 As[128 * 32];   // 8 KB, row-major [m][k]
    __shared__ __align__(16) u16 Bs[128 * 32];   // 8 KB, row-major [n][k]
    const int tid  = threadIdx.x;
    const int lane = tid & 63;
    const int wave = tid >> 6;
    const int wm = (wave >> 1) * 64, wn = (wave & 1) * 64;
    const int quad = lane >> 4, lr = lane & 15;
    int m0, n0;
    if (FUSE) {
        const int blk = blockIdx.x;
        const int xcd = blk & 7, s = blk >> 3;
        const int tx = s & 7, ty = ((s >> 3) << 3) | xcd;
        m0 = ty * 128; n0 = tx * 128;
    } else {
        m0 = blockIdx.y * 128; n0 = blockIdx.x * 128;
    }

    const int r0 = tid >> 2, c0 = (tid & 3) * 8;
    const u16* gA = A  + (size_t)(m0 + r0) * K + c0;
    const u16* gB = BT + (size_t)(n0 + r0) * K + c0;
    u16* lA0 = As + wave * 512;  u16* lA1 = lA0 + 2048;
    u16* lB0 = Bs + wave * 512;  u16* lB1 = lB0 + 2048;
    const size_t rowStride = (size_t)64 * K;

    floatx4 acc[4][4] = {};

    for (int k0 = 0; k0 < K; k0 += 32) {
        async_copy16(lA0, gA + k0);
        async_copy16(lA1, gA + rowStride + k0);
        async_copy16(lB0, gB + k0);
        async_copy16(lB1, gB + rowStride + k0);
        __syncthreads();
        bf16x8 af[4], bfr[4];
#pragma unroll
        for (int i = 0; i < 4; ++i)
            af[i] = *(const bf16x8*)(As + (wm + i * 16 + lr) * 32 + quad * 8);
#pragma unroll
        for (int j = 0; j < 4; ++j)
            bfr[j] = *(const bf16x8*)(Bs + (wn + j * 16 + lr) * 32 + quad * 8);
        // swapped operands: acc[i][j] holds transposed fragment (see header)
#pragma unroll
        for (int i = 0; i < 4; ++i)
#pragma unroll
            for (int j = 0; j < 4; ++j)
                acc[i][j] = __builtin_amdgcn_mfma_f32_16x16x32_bf16(bfr[j], af[i], acc[i][j], 0, 0, 0);
        __syncthreads();
    }

    // Epilogue. frag (i,j): m = wm+i*16+lr (lane-major), n = wn+j*16+quad*4+rg (reg-major)
    const int b = m0 >> 10;              // 128-row tile never crosses a batch
    float4 hqv[4], wpv[4];
    if (FUSE) {
#pragma unroll
        for (int j = 0; j < 4; ++j) {
            const int nb = n0 + wn + j * 16 + quad * 4;
            hqv[j] = *(const float4*)(shift + b * 1024 + nb);
            wpv[j] = *(const float4*)(wv + nb);
        }
    }
#pragma unroll
    for (int i = 0; i < 4; ++i) {
        const int m = m0 + wm + i * 16 + lr;
        float tsum = 0.f;
#pragma unroll
        for (int j = 0; j < 4; ++j) {
            const int nb = n0 + wn + j * 16 + quad * 4;
            uint2 st;
            st.x = pack_bf16x2(acc[i][j][0], acc[i][j][1]);
            st.y = pack_bf16x2(acc[i][j][2], acc[i][j][3]);
            *(uint2*)(C + (size_t)m * N + nb) = st;
            if (FUSE) {
                tsum += fast_tanh(acc[i][j][0] + hqv[j].x) * wpv[j].x;
                tsum += fast_tanh(acc[i][j][1] + hqv[j].y) * wpv[j].y;
                tsum += fast_tanh(acc[i][j][2] + hqv[j].z) * wpv[j].z;
                tsum += fast_tanh(acc[i][j][3] + hqv[j].w) * wpv[j].w;
            }
        }
        if (FUSE) {
            // reduce over quads (cols): lanes lr fixed, quad = bits 4..5
            tsum += __shfl_xor(tsum, 16, 64);
            tsum += __shfl_xor(tsum, 32, 64);
            if (lane < 16)
                atomicAdd(&sOut[m], tsum);
        }
    }
}

// ---------------------------------------------------------------------------
// s[row] = mask ? sum_a tanh(R[row,a] + shift[row/shiftDiv, a]) * wv[a] : -1e30
// One wave per row; R is bf16 [rows,1024].
// ---------------------------------------------------------------------------
__global__ __launch_bounds__(256) void tanh_dot_kernel(
    const u16* __restrict__ R, const float* __restrict__ shift,
    const float* __restrict__ wv, const float* __restrict__ mask,
    float* __restrict__ out, int shiftDiv)
{
    const int row  = blockIdx.x * 4 + (threadIdx.x >> 6);
    const int lane = threadIdx.x & 63;
    const u16* rp   = R + (size_t)row * 1024;
    const float* sp = shift + (size_t)(row / shiftDiv) * 1024;
    float acc = 0.f;
#pragma unroll
    for (int p = 0; p < 2; ++p) {
        const int a0 = (p * 64 + lane) * 8;
        uint4  rv = *(const uint4*)(rp + a0);
        float4 s0 = *(const float4*)(sp + a0);
        float4 s1 = *(const float4*)(sp + a0 + 4);
        float4 w0 = *(const float4*)(wv + a0);
        float4 w1 = *(const float4*)(wv + a0 + 4);
        acc += fast_tanh(bf16_lo(rv.x) + s0.x) * w0.x;
        acc += fast_tanh(bf16_hi(rv.x) + s0.y) * w0.y;
        acc += fast_tanh(bf16_lo(rv.y) + s0.z) * w0.z;
        acc += fast_tanh(bf16_hi(rv.y) + s0.w) * w0.w;
        acc += fast_tanh(bf16_lo(rv.z) + s1.x) * w1.x;
        acc += fast_tanh(bf16_hi(rv.z) + s1.y) * w1.y;
        acc += fast_tanh(bf16_lo(rv.w) + s1.z) * w1.z;
        acc += fast_tanh(bf16_hi(rv.w) + s1.w) * w1.w;
    }
#pragma unroll
    for (int off = 32; off > 0; off >>= 1)
        acc += __shfl_down(acc, off, 64);
    if (lane == 0)
        out[row] = (mask[row] > 0.f) ? acc : -1e30f;
}

// ---------------------------------------------------------------------------
// out[idx] = mask[idx] > 0 ? sIn[idx] : -1e30
// ---------------------------------------------------------------------------
__global__ __launch_bounds__(256) void mask_kernel(
    const float* __restrict__ sIn, const float* __restrict__ mask, float* __restrict__ out)
{
    const int idx = blockIdx.x * 256 + threadIdx.x;
    out[idx] = (mask[idx] > 0.f) ? sIn[idx] : -1e30f;
}

// ---------------------------------------------------------------------------
// Question pool: softmax over TQ=64 then hidden[b,h] = sum_t alpha[t]*q[b,t,h]
// ---------------------------------------------------------------------------
__global__ __launch_bounds__(256) void pool_q_kernel(
    const float* __restrict__ s, const float* __restrict__ seq, float* __restrict__ hidden)
{
    const int b = blockIdx.x, tid = threadIdx.x;
    __shared__ float alpha[64];
    if (tid < 64) {
        float v = s[b * 64 + tid];
        float m = v;
#pragma unroll
        for (int off = 32; off > 0; off >>= 1) m = fmaxf(m, __shfl_xor(m, off, 64));
        float e = __expf(v - m);
        float sum = e;
#pragma unroll
        for (int off = 32; off > 0; off >>= 1) sum += __shfl_xor(sum, off, 64);
        alpha[tid] = e * __builtin_amdgcn_rcpf(sum);
    }
    __syncthreads();
    float acc[4] = {0.f, 0.f, 0.f, 0.f};
    const float* base = seq + (size_t)b * 64 * 1024;
#pragma unroll 4
    for (int t = 0; t < 64; ++t) {
        const float a = alpha[t];
#pragma unroll
        for (int j = 0; j < 4; ++j)
            acc[j] += a * base[(size_t)t * 1024 + tid + j * 256];
    }
#pragma unroll
    for (int j = 0; j < 4; ++j) hidden[b * 1024 + tid + j * 256] = acc[j];
}

// ---------------------------------------------------------------------------
// Passage pool over bf16 passage copy, t-split.
// grid (64 b, 4 col-chunks of 256, 4 t-chunks of 256); atomicAdd into pooled.
// ---------------------------------------------------------------------------
__global__ __launch_bounds__(256) void pool_p_kernel(
    const float* __restrict__ s, const u16* __restrict__ seq, float* __restrict__ pooled)
{
    const int b = blockIdx.x, tid = threadIdx.x;
    const int col = blockIdx.y * 256 + tid;
    const int t0 = blockIdx.z * 256;
    const int lane = tid & 63, wid = tid >> 6;
    __shared__ float alpha[1024];
    __shared__ float redm[4], reds[4];
    const float* sr = s + b * 1024;
    float v[4];
    float m = -3.4e38f;
#pragma unroll
    for (int j = 0; j < 4; ++j) { v[j] = sr[tid + j * 256]; m = fmaxf(m, v[j]); }
#pragma unroll
    for (int off = 32; off > 0; off >>= 1) m = fmaxf(m, __shfl_xor(m, off, 64));
    if (lane == 0) redm[wid] = m;
    __syncthreads();
    m = fmaxf(fmaxf(redm[0], redm[1]), fmaxf(redm[2], redm[3]));
    float sum = 0.f;
#pragma unroll
    for (int j = 0; j < 4; ++j) { float e = __expf(v[j] - m); alpha[tid + j * 256] = e; sum += e; }
#pragma unroll
    for (int off = 32; off > 0; off >>= 1) sum += __shfl_xor(sum, off, 64);
    if (lane == 0) reds[wid] = sum;
    __syncthreads();
    const float rs = __builtin_amdgcn_rcpf(reds[0] + reds[1] + reds[2] + reds[3]);
    float acc = 0.f;
    const u16* base = seq + (size_t)b * (1024 * 1024) + (size_t)t0 * 1024 + col;
#pragma unroll 8
    for (int t = 0; t < 256; ++t)
        acc += alpha[t0 + t] * bf16f(base[(size_t)t * 1024]);
    atomicAdd(&pooled[b * 1024 + col], acc * rs);
}

// ---------------------------------------------------------------------------
// Small fp32 GEMM: out[64,N] = X[64,K] @ B  (B is [N,K] if BT else [K,N]).
// 64x64 tile, BK=16, 4x4 micro-tile. blockIdx.y picks operand set.
// If SPLIT: blockIdx.z splits K into 4 chunks, atomicAdd epilogue (out must be 0).
// ---------------------------------------------------------------------------
template <bool BT, bool SPLIT>
__global__ __launch_bounds__(256) void small_gemm_kernel(
    const float* __restrict__ X0, const float* __restrict__ X1,
    const float* __restrict__ B0, const float* __restrict__ B1,
    float* __restrict__ out0, float* __restrict__ out1, int K, int N)
{
    const float* X  = blockIdx.y ? X1 : X0;
    const float* Bm = blockIdx.y ? B1 : B0;
    float* out      = blockIdx.y ? out1 : out0;
    const int n0 = blockIdx.x * 64;
    const int kBeg = SPLIT ? (int)blockIdx.z * (K >> 2) : 0;
    const int kEnd = SPLIT ? kBeg + (K >> 2) : K;
    const int tid = threadIdx.x, tx = tid & 15, ty = tid >> 4;
    __shared__ float Xs[64][17];
    __shared__ float Bs[64][17];
    float acc[4][4] = {};
    for (int kc = kBeg; kc < kEnd; kc += 16) {
        {
            int e = tid * 4, row = e >> 4, kk = e & 15;
            float4 v = *(const float4*)(X + (size_t)row * K + kc + kk);
            Xs[row][kk] = v.x; Xs[row][kk + 1] = v.y; Xs[row][kk + 2] = v.z; Xs[row][kk + 3] = v.w;
        }
        if (BT) {
            int e = tid * 4, n = e >> 4, kk = e & 15;
            float4 v = *(const float4*)(Bm + (size_t)(n0 + n) * K + kc + kk);
            Bs[n][kk] = v.x; Bs[n][kk + 1] = v.y; Bs[n][kk + 2] = v.z; Bs[n][kk + 3] = v.w;
        } else {
            int c = tid & 63, kb = tid >> 6;
#pragma unroll
            for (int u = 0; u < 4; ++u) {
                int k = kb + u * 4;
                Bs[c][k] = Bm[(size_t)(kc + k) * N + n0 + c];
            }
        }
        __syncthreads();
#pragma unroll
        for (int k = 0; k < 16; ++k) {
            float xr[4], br[4];
#pragma unroll
            for (int bi = 0; bi < 4; ++bi) xr[bi] = Xs[ty * 4 + bi][k];
#pragma unroll
            for (int ni = 0; ni < 4; ++ni) br[ni] = Bs[tx * 4 + ni][k];
#pragma unroll
            for (int bi = 0; bi < 4; ++bi)
#pragma unroll
                for (int ni = 0; ni < 4; ++ni)
                    acc[bi][ni] += xr[bi] * br[ni];
        }
        __syncthreads();
    }
#pragma unroll
    for (int bi = 0; bi < 4; ++bi)
#pragma unroll
        for (int ni = 0; ni < 4; ++ni) {
            float* p = out + (size_t)(ty * 4 + bi) * N + n0 + tx * 4 + ni;
            if (SPLIT) atomicAdd(p, acc[bi][ni]);
            else       *p = acc[bi][ni];
        }
}

// ---------------------------------------------------------------------------
// GRU cell combine (torch.nn.GRUCell math), biases applied here.
// ---------------------------------------------------------------------------
__global__ __launch_bounds__(256) void gru_combine_kernel(
    const float* __restrict__ gi, const float* __restrict__ gh,
    const float* __restrict__ bih, const float* __restrict__ bhh,
    const float* __restrict__ h, float* __restrict__ out)
{
    const int idx = blockIdx.x * 256 + threadIdx.x;   // 0..65535
    const int b = idx >> 10, j = idx & 1023;
    const float* gib = gi + (size_t)b * 3072;
    const float* ghb = gh + (size_t)b * 3072;
    float ir = gib[j] + bih[j],                hr = ghb[j] + bhh[j];
    float iz = gib[1024 + j] + bih[1024 + j],  hz = ghb[1024 + j] + bhh[1024 + j];
    float in_ = gib[2048 + j] + bih[2048 + j], hn = ghb[2048 + j] + bhh[2048 + j];
    float r = fast_sigmoid(ir + hr);
    float z = fast_sigmoid(iz + hz);
    float n = fast_tanh(in_ + r * hn);
    out[idx] = (1.f - z) * n + z * h[idx];
}

// ---------------------------------------------------------------------------
extern "C" void kernel_launch(void* const* d_in, const int* in_sizes, int n_in,
                              void* d_out, int out_size, void* d_ws, size_t ws_size,
                              hipStream_t stream)
{
    const float* question      = (const float*)d_in[0];   // [64,64,1024]
    const float* question_mask = (const float*)d_in[1];   // [64,64]
    const float* passage       = (const float*)d_in[2];   // [64,1024,1024]
    const float* passage_mask  = (const float*)d_in[3];   // [64,1024]
    const float* V_q  = (const float*)d_in[4];            // [1024]
    const float* Wk_q = (const float*)d_in[5];            // [1024,1024]
    const float* Wq_q = (const float*)d_in[6];
    const float* w_q  = (const float*)d_in[7];
    const float* Wk_p = (const float*)d_in[8];
    const float* Wq_p = (const float*)d_in[9];
    const float* w_p  = (const float*)d_in[10];
    const float* W_ih = (const float*)d_in[11];           // [3072,1024]
    const float* W_hh = (const float*)d_in[12];
    const float* b_ih = (const float*)d_in[13];
    const float* b_hh = (const float*)d_in[14];

    char* ws = (char*)d_ws;
    auto alloc = [&](size_t bytes) { char* p = ws; ws += (bytes + 255) & ~(size_t)255; return p; };
    // --- contiguous zero-init region (single memset) ---
    float* vWq    = (float*)alloc(1024 * 4);              // 4 KB
    float* hWq    = (float*)alloc(65536 * 4);             // 256 KB
    float* oWq    = (float*)alloc(65536 * 4);             // 256 KB
    float* sBegin = (float*)alloc(65536 * 4);             // 256 KB
    float* pooled = (float*)alloc(65536 * 4);             // 256 KB
    const size_t zeroBytes = (size_t)(1024 + 4 * 65536) * 4;
    // --- rest ---
    u16* WkQT  = (u16*)alloc((size_t)1024 * 1024 * 2);    // Wk_q^T bf16 [A,K]
    u16* WkPT  = (u16*)alloc((size_t)1024 * 1024 * 2);    // Wk_p^T bf16 [A,K]
    u16* pbf   = (u16*)alloc((size_t)65536 * 1024 * 2);   // passage bf16 (128 MB)
    u16* qbf   = (u16*)alloc((size_t)4096 * 1024 * 2);    // question bf16
    u16* qWk   = (u16*)alloc((size_t)4096 * 1024 * 2);    // question@Wk_q bf16
    u16* pWk   = (u16*)alloc((size_t)65536 * 1024 * 2);   // passage@Wk_p bf16 (128 MB)
    float* s_q    = (float*)alloc(4096 * 4);
    float* hidden = (float*)alloc(65536 * 4);
    float* gi     = (float*)alloc((size_t)64 * 3072 * 4);
    float* gh     = (float*)alloc((size_t)64 * 3072 * 4);
    float* gout   = (float*)alloc(65536 * 4);

    float* ans_begin = (float*)d_out;          // [64,1024]
    float* ans_end   = ans_begin + 65536;      // [64,1024]

    // 1. zero-init all atomicAdd targets in one shot
    hipMemsetAsync(vWq, 0, zeroBytes, stream);

    // 2-3. bulk fp32->bf16 conversions + weight transposes (merged)
    conv2_bf16_kernel<<<dim3(34816), 256, 0, stream>>>(passage, pbf, question, qbf);
    transpose2_bf16_kernel<<<dim3(32, 32, 2), 256, 0, stream>>>(Wk_q, WkQT, Wk_p, WkPT);

    // 4-8. question path (produces hWq for the fused big-GEMM epilogue)
    gemm_bf16_kernel<false><<<dim3(8, 32), 256, 0, stream>>>(
        qbf, WkQT, qWk, nullptr, nullptr, nullptr, 1024, 1024);
    vq_proj_kernel<<<dim3(4, 8), 256, 0, stream>>>(V_q, Wq_q, vWq);
    tanh_dot_kernel<<<dim3(1024), 256, 0, stream>>>(qWk, vWq, w_q, question_mask, s_q, 4096);
    pool_q_kernel<<<dim3(64), 256, 0, stream>>>(s_q, question, hidden);
    small_gemm_kernel<false, true><<<dim3(16, 1, 4), 256, 0, stream>>>(
        hidden, hidden, Wq_p, Wq_p, hWq, hWq, 1024, 1024);

    // 9-10. big GEMM (dominant): pWk = passage @ Wk_p, fused begin-logit partials
    gemm_bf16_kernel<true><<<dim3(4096), 256, 0, stream>>>(
        pbf, WkPT, pWk, hWq, w_p, sBegin, 1024, 1024);
    mask_kernel<<<dim3(256), 256, 0, stream>>>(sBegin, passage_mask, ans_begin);

    // 11-13. passage pool + GRU step
    pool_p_kernel<<<dim3(64, 4, 4), 256, 0, stream>>>(ans_begin, pbf, pooled);
    small_gemm_kernel<true, false><<<dim3(48, 2), 256, 0, stream>>>(
        pooled, hidden, W_ih, W_hh, gi, gh, 1024, 3072);
    gru_combine_kernel<<<dim3(256), 256, 0, stream>>>(gi, gh, b_ih, b_hh, hidden, gout);

    // 14-15. end logits
    small_gemm_kernel<false, true><<<dim3(16, 1, 4), 256, 0, stream>>>(
        gout, gout, Wq_p, Wq_p, oWq, oWq, 1024, 1024);
    tanh_dot_kernel<<<dim3(16384), 256, 0, stream>>>(pWk, oWq, w_p, passage_mask, ans_end, 1024);
}